// Round 4
// baseline (101.693 us; speedup 1.0000x reference)
//
#include <hip/hip_runtime.h>
#include <hip/hip_bf16.h>
#include <math.h>

#define B_    8
#define C_    256
#define L_    4096
#define OCH_  256

typedef __attribute__((ext_vector_type(8)))  short bf16x8;
typedef __attribute__((ext_vector_type(16))) float f32x16;
typedef __attribute__((ext_vector_type(4)))  int   i32x4;

static __device__ __forceinline__ unsigned short bf16_rne(float f) {
    unsigned u = __float_as_uint(f);
    unsigned r = u + 0x7FFFu + ((u >> 16) & 1u);
    return (unsigned short)(r >> 16);
}

// ---------------------------------------------------------------------------
// K0: split W[o][c][k] -> k-major bf16 hi/lo: W*[o][k*256+c]
// ---------------------------------------------------------------------------
__global__ void k_split(const float* __restrict__ W,
                        unsigned short* __restrict__ Whi,
                        unsigned short* __restrict__ Wlo) {
    int i = blockIdx.x * 256 + threadIdx.x;          // o*768 + c*3 + k
    if (i >= OCH_ * C_ * 3) return;
    int k = i % 3;
    int c = (i / 3) & 255;
    int o = i / 768;
    float w = W[i];
    unsigned short hb = bf16_rne(w);
    float hi = __uint_as_float((unsigned)hb << 16);
    int dst = o * 768 + k * 256 + c;
    Whi[dst] = hb;
    Wlo[dst] = bf16_rne(w - hi);
}

// ---------------------------------------------------------------------------
// K1: fused offset-net + sample + split-precision MFMA GEMM.
// Block = 256 thr (4 waves) -> 256o x 64l. Wave wv owns o-slice wv*64..+64
// (m=2 x 32-row MFMA frags), nf=2 (2 x 32 cols). K=768 k-major, chunk 128.
// LDS tile slot-major: s[slot][l] (slot = kk/8) -> conflict-free b128 r/w.
// Double-buffered; gathers for chunk ch+1 prefetched to regs during MFMA ch.
// acc = Whi*Shi + Whi*Slo + Wlo*Shi  (f32 accum via 32x32x16 MFMA)
// ---------------------------------------------------------------------------
__global__ __launch_bounds__(256, 2) void k_conv(
        const float* __restrict__ x,
        const unsigned short* __restrict__ Whi,
        const unsigned short* __restrict__ Wlo,
        const float* __restrict__ bias,
        const float* __restrict__ w1, const float* __restrict__ b1,
        const float* __restrict__ w2, const float* __restrict__ b2,
        float* __restrict__ out) {
    __shared__ i32x4  sHi[2][16][64];                // 32 KB
    __shared__ i32x4  sLo[2][16][64];                // 32 KB
    __shared__ float  sOm[64][37];                   // 9.25 KB
    __shared__ float4 cLds[3][64];                   // 3 KB

    const int tid  = threadIdx.x;
    const int lane = tid & 63;
    const int wv   = tid >> 6;                       // 0..3
    const int blk  = blockIdx.x;
    const int b    = blk & 7;                        // XCD affinity: xcd ~ b
    const int l0   = (blk >> 3) * 64;

    const float* xb = x + (size_t)b * (C_ * L_);

    // ================= offset network (wave wv = group wv) =================
    {
        const float* xg = xb + (size_t)(wv * 64) * L_ + (l0 + lane);
        float h[16];
        #pragma unroll
        for (int o = 0; o < 16; ++o) h[o] = b1[wv * 16 + o];
        #pragma unroll 4
        for (int cg = 0; cg < 64; ++cg) {
            float xv = xg[(size_t)cg * L_];
            const float* w1p = w1 + (wv * 16) * 64 + cg;
            #pragma unroll
            for (int o = 0; o < 16; ++o) h[o] = fmaf(xv, w1p[o * 64], h[o]);
        }
        float om9[9];
        #pragma unroll
        for (int j = 0; j < 9; ++j) om9[j] = b2[wv * 9 + j];
        #pragma unroll
        for (int o = 0; o < 16; ++o) {
            float a  = h[o];
            float hv = 0.5f * a * (1.0f + erff(a * 0.70710678118654752f));
            const float* w2p = w2 + wv * 144 + o;    // w2[g][j][o]
            #pragma unroll
            for (int j = 0; j < 9; ++j) om9[j] = fmaf(hv, w2p[j * 16], om9[j]);
        }
        #pragma unroll
        for (int j = 0; j < 9; ++j) sOm[lane][wv * 9 + j] = om9[j];
    }
    __syncthreads();
    if (wv == 0) {                                   // softmax + coef, col=lane
        float om[36];
        #pragma unroll
        for (int j = 0; j < 36; ++j) om[j] = sOm[lane][j];
        om[1] = 0.0f; om[3] = 0.0f; om[5] = 0.0f;
        float m = om[3];
        #pragma unroll
        for (int j = 4; j < 36; ++j) m = fmaxf(m, om[j]);
        float ssum = 0.0f;
        #pragma unroll
        for (int j = 3; j < 36; ++j) ssum += expf(om[j] - m);
        float inv = 1.0f / ssum;
        int l = l0 + lane;
        float base = -1.0f + 2.0f * (float)l / (float)(L_ - 1);
        #pragma unroll
        for (int t = 0; t < 3; ++t) {
            float mod  = expf(om[3 + t] - m) * inv;
            float off  = om[2 * t] * (2.0f / (float)L_);
            float grid = base + (-0.5f + 0.5f * (float)t) + off;
            float pp   = (grid + 1.0f) * 0.5f * (float)(L_ - 1);
            float fp   = floorf(pp);
            int i0 = (int)fp, i1 = i0 + 1;
            float w = pp - fp;
            float v0 = (i0 >= 0 && i0 < L_) ? 1.0f : 0.0f;
            float v1 = (i1 >= 0 && i1 < L_) ? 1.0f : 0.0f;
            int i0c = min(max(i0, 0), L_ - 1);
            int i1c = min(max(i1, 0), L_ - 1);
            cLds[t][lane] = make_float4((1.0f - w) * v0 * mod, w * v1 * mod,
                                        __int_as_float(i0c), __int_as_float(i1c));
        }
    }
    __syncthreads();

    int i0a[3], i1a[3]; float c0a[3], c1a[3];
    #pragma unroll
    for (int t = 0; t < 3; ++t) {
        float4 cf = cLds[t][lane];
        c0a[t] = cf.x; c1a[t] = cf.y;
        i0a[t] = __float_as_int(cf.z); i1a[t] = __float_as_int(cf.w);
    }

    // ================= main GEMM =================
    f32x16 acc00, acc01, acc10, acc11;
    #pragma unroll
    for (int i = 0; i < 16; ++i) { acc00[i] = 0.f; acc01[i] = 0.f; acc10[i] = 0.f; acc11[i] = 0.f; }

    const int q   = lane >> 5;                       // 0/1: k-half within frag
    const int l31 = lane & 31;
    const unsigned short* Wh0 = Whi + (size_t)(wv * 64 + l31) * 768;
    const unsigned short* Wh1 = Wh0 + 32 * 768;
    const unsigned short* Wl0 = Wlo + (size_t)(wv * 64 + l31) * 768;
    const unsigned short* Wl1 = Wl0 + 32 * 768;

    float g0[32], g1[32];

    // ---- prologue: gather + pack chunk 0 (rows wv*32..+32, tap 0) ----
    {
        const float* xc = xb + (size_t)(wv * 32) * L_;
        int i0 = i0a[0], i1 = i1a[0];
        #pragma unroll
        for (int j = 0; j < 32; ++j) {
            g0[j] = xc[(size_t)j * L_ + i0];
            g1[j] = xc[(size_t)j * L_ + i1];
        }
        float c0 = c0a[0], c1 = c1a[0];
        #pragma unroll
        for (int sp = 0; sp < 4; ++sp) {
            union { unsigned short us[8]; i32x4 v; } ph, pl;
            #pragma unroll
            for (int e = 0; e < 8; ++e) {
                float sv = fmaf(g0[sp * 8 + e], c0, g1[sp * 8 + e] * c1);
                unsigned u = __float_as_uint(sv);
                ph.us[e] = (unsigned short)(u >> 16);
                pl.us[e] = bf16_rne(sv - __uint_as_float(u & 0xFFFF0000u));
            }
            sHi[0][wv * 4 + sp][lane] = ph.v;
            sLo[0][wv * 4 + sp][lane] = pl.v;
        }
    }
    __syncthreads();

    #pragma unroll 2
    for (int ch = 0; ch < 6; ++ch) {
        const int buf = ch & 1;
        // ---- prefetch gathers for chunk ch+1 (latency hidden by MFMA) ----
        if (ch < 5) {
            int kk0 = (ch + 1) * 128 + wv * 32;
            int tap = kk0 >> 8;
            int i0 = tap == 2 ? i0a[2] : tap == 1 ? i0a[1] : i0a[0];
            int i1 = tap == 2 ? i1a[2] : tap == 1 ? i1a[1] : i1a[0];
            const float* xc = xb + (size_t)(kk0 & 255) * L_;
            #pragma unroll
            for (int j = 0; j < 32; ++j) {
                g0[j] = xc[(size_t)j * L_ + i0];
                g1[j] = xc[(size_t)j * L_ + i1];
            }
        }
        // ---- MFMA phase on buf ----
        #pragma unroll
        for (int ks = 0; ks < 8; ++ks) {
            const int kg = ch * 128 + ks * 16 + q * 8;
            bf16x8 ah0 = *(const bf16x8*)(Wh0 + kg);
            bf16x8 ah1 = *(const bf16x8*)(Wh1 + kg);
            bf16x8 al0 = *(const bf16x8*)(Wl0 + kg);
            bf16x8 al1 = *(const bf16x8*)(Wl1 + kg);
            const i32x4* bp = &sHi[buf][ks * 2 + q][l31];
            const i32x4* lp = &sLo[buf][ks * 2 + q][l31];
            bf16x8 bh0 = *(const bf16x8*)bp;
            bf16x8 bh1 = *(const bf16x8*)(bp + 32);
            bf16x8 bl0 = *(const bf16x8*)lp;
            bf16x8 bl1 = *(const bf16x8*)(lp + 32);
            __builtin_amdgcn_s_setprio(1);
            acc00 = __builtin_amdgcn_mfma_f32_32x32x16_bf16(ah0, bh0, acc00, 0, 0, 0);
            acc01 = __builtin_amdgcn_mfma_f32_32x32x16_bf16(ah0, bh1, acc01, 0, 0, 0);
            acc10 = __builtin_amdgcn_mfma_f32_32x32x16_bf16(ah1, bh0, acc10, 0, 0, 0);
            acc11 = __builtin_amdgcn_mfma_f32_32x32x16_bf16(ah1, bh1, acc11, 0, 0, 0);
            acc00 = __builtin_amdgcn_mfma_f32_32x32x16_bf16(ah0, bl0, acc00, 0, 0, 0);
            acc01 = __builtin_amdgcn_mfma_f32_32x32x16_bf16(ah0, bl1, acc01, 0, 0, 0);
            acc10 = __builtin_amdgcn_mfma_f32_32x32x16_bf16(ah1, bl0, acc10, 0, 0, 0);
            acc11 = __builtin_amdgcn_mfma_f32_32x32x16_bf16(ah1, bl1, acc11, 0, 0, 0);
            acc00 = __builtin_amdgcn_mfma_f32_32x32x16_bf16(al0, bh0, acc00, 0, 0, 0);
            acc01 = __builtin_amdgcn_mfma_f32_32x32x16_bf16(al0, bh1, acc01, 0, 0, 0);
            acc10 = __builtin_amdgcn_mfma_f32_32x32x16_bf16(al1, bh0, acc10, 0, 0, 0);
            acc11 = __builtin_amdgcn_mfma_f32_32x32x16_bf16(al1, bh1, acc11, 0, 0, 0);
            __builtin_amdgcn_s_setprio(0);
        }
        // ---- pack + write chunk ch+1 into other buffer ----
        if (ch < 5) {
            int kk0 = (ch + 1) * 128 + wv * 32;
            int tap = kk0 >> 8;
            float c0 = tap == 2 ? c0a[2] : tap == 1 ? c0a[1] : c0a[0];
            float c1 = tap == 2 ? c1a[2] : tap == 1 ? c1a[1] : c1a[0];
            const int nbuf = buf ^ 1;
            #pragma unroll
            for (int sp = 0; sp < 4; ++sp) {
                union { unsigned short us[8]; i32x4 v; } ph, pl;
                #pragma unroll
                for (int e = 0; e < 8; ++e) {
                    float sv = fmaf(g0[sp * 8 + e], c0, g1[sp * 8 + e] * c1);
                    unsigned u = __float_as_uint(sv);
                    ph.us[e] = (unsigned short)(u >> 16);
                    pl.us[e] = bf16_rne(sv - __uint_as_float(u & 0xFFFF0000u));
                }
                sHi[nbuf][wv * 4 + sp][lane] = ph.v;
                sLo[nbuf][wv * 4 + sp][lane] = pl.v;
            }
        }
        __syncthreads();
    }

    // ---- epilogue: bias + store. D: col=lane&31, row=(reg&3)+8*(reg>>2)+4*q
    #pragma unroll
    for (int reg = 0; reg < 16; ++reg) {
        int rr = (reg & 3) + 8 * (reg >> 2) + 4 * q;
        {   // m = 0
            int o = wv * 64 + rr;
            float bv = bias[o];
            float* op = out + ((size_t)b * 256 + o) * L_ + l0 + l31;
            op[0]  = acc00[reg] + bv;
            op[32] = acc01[reg] + bv;
        }
        {   // m = 1
            int o = wv * 64 + 32 + rr;
            float bv = bias[o];
            float* op = out + ((size_t)b * 256 + o) * L_ + l0 + l31;
            op[0]  = acc10[reg] + bv;
            op[32] = acc11[reg] + bv;
        }
    }
}

// ---------------------------------------------------------------------------
extern "C" void kernel_launch(void* const* d_in, const int* in_sizes, int n_in,
                              void* d_out, int out_size, void* d_ws, size_t ws_size,
                              hipStream_t stream) {
    const float* x      = (const float*)d_in[0];
    const float* weight = (const float*)d_in[1];
    const float* bias   = (const float*)d_in[2];
    const float* w1     = (const float*)d_in[3];
    const float* b1     = (const float*)d_in[4];
    const float* w2     = (const float*)d_in[5];
    const float* b2     = (const float*)d_in[6];
    float* out = (float*)d_out;

    unsigned short* Whi = (unsigned short*)d_ws;                  // 384 KB
    unsigned short* Wlo = Whi + OCH_ * C_ * 3;                    // 384 KB

    k_split<<<(OCH_ * C_ * 3 + 255) / 256, 256, 0, stream>>>(weight, Whi, Wlo);
    k_conv<<<B_ * (L_ / 64), 256, 0, stream>>>(x, Whi, Wlo, bias,
                                               w1, b1, w2, b2, out);
}

// Round 6
// 95.536 us; speedup vs baseline: 1.0645x; 1.0645x over previous
//
#include <hip/hip_runtime.h>
#include <hip/hip_bf16.h>
#include <math.h>

#define B_    8
#define C_    256
#define L_    4096
#define OCH_  256

typedef __attribute__((ext_vector_type(8)))  short bf16x8;
typedef __attribute__((ext_vector_type(16))) float f32x16;
typedef __attribute__((ext_vector_type(4)))  int   i32x4;

static __device__ __forceinline__ unsigned short bf16_rne(float f) {
    unsigned u = __float_as_uint(f);
    unsigned r = u + 0x7FFFu + ((u >> 16) & 1u);
    return (unsigned short)(r >> 16);
}

// ---------------------------------------------------------------------------
// K0: split W[o][c][k] -> k-major bf16 hi/lo: W*[o][k*256+c]
// ---------------------------------------------------------------------------
__global__ void k_split(const float* __restrict__ W,
                        unsigned short* __restrict__ Whi,
                        unsigned short* __restrict__ Wlo) {
    int i = blockIdx.x * 256 + threadIdx.x;          // o*768 + c*3 + k
    if (i >= OCH_ * C_ * 3) return;
    int k = i % 3;
    int c = (i / 3) & 255;
    int o = i / 768;
    float w = W[i];
    unsigned short hb = bf16_rne(w);
    float hi = __uint_as_float((unsigned)hb << 16);
    int dst = o * 768 + k * 256 + c;
    Whi[dst] = hb;
    Wlo[dst] = bf16_rne(w - hi);
}

// ---------------------------------------------------------------------------
// K1: offset network (separate kernel; overlaps across 512 blocks).
// Wave g computes group g; wave 0 finishes softmax and emits window-form
// coef[(b*3+t)*L + l] = { d0, d1, bits(i0f2), 0 } :
//   sampled = x[i0f2]*d0 + x[i0f2+1]*d1   (all clamp/validity pre-folded)
// ---------------------------------------------------------------------------
__global__ __launch_bounds__(256) void k_offsets(
        const float* __restrict__ x,
        const float* __restrict__ w1, const float* __restrict__ b1,
        const float* __restrict__ w2, const float* __restrict__ b2,
        float4* __restrict__ coef) {
    __shared__ float sOm[64][37];
    int tid  = threadIdx.x;
    int lane = tid & 63;
    int g    = tid >> 6;
    int blk  = blockIdx.x;
    int b    = blk & 7;                              // XCD affinity
    int l0   = (blk >> 3) << 6;
    int l    = l0 + lane;

    const float* xg = x + (size_t)b * C_ * L_ + (size_t)(g * 64) * L_ + l;

    float h[16];
    #pragma unroll
    for (int o = 0; o < 16; ++o) h[o] = b1[g * 16 + o];
    #pragma unroll 4
    for (int cg = 0; cg < 64; ++cg) {
        float xv = xg[(size_t)cg * L_];
        const float* w1p = w1 + (g * 16) * 64 + cg;
        #pragma unroll
        for (int o = 0; o < 16; ++o) h[o] = fmaf(xv, w1p[o * 64], h[o]);
    }
    float om9[9];
    #pragma unroll
    for (int j = 0; j < 9; ++j) om9[j] = b2[g * 9 + j];
    #pragma unroll
    for (int o = 0; o < 16; ++o) {
        float a  = h[o];
        float hv = 0.5f * a * (1.0f + erff(a * 0.70710678118654752f));
        const float* w2p = w2 + g * 144 + o;         // w2[g][j][o]
        #pragma unroll
        for (int j = 0; j < 9; ++j) om9[j] = fmaf(hv, w2p[j * 16], om9[j]);
    }
    #pragma unroll
    for (int j = 0; j < 9; ++j) sOm[lane][g * 9 + j] = om9[j];
    __syncthreads();
    if (g != 0) return;

    float om[36];
    #pragma unroll
    for (int j = 0; j < 36; ++j) om[j] = sOm[lane][j];
    om[1] = 0.0f; om[3] = 0.0f; om[5] = 0.0f;
    float m = om[3];
    #pragma unroll
    for (int j = 4; j < 36; ++j) m = fmaxf(m, om[j]);
    float ssum = 0.0f;
    #pragma unroll
    for (int j = 3; j < 36; ++j) ssum += expf(om[j] - m);
    float inv = 1.0f / ssum;

    float base = -1.0f + 2.0f * (float)l / (float)(L_ - 1);
    #pragma unroll
    for (int t = 0; t < 3; ++t) {
        float mod  = expf(om[3 + t] - m) * inv;
        float off  = om[2 * t] * (2.0f / (float)L_);
        float grid = base + (-0.5f + 0.5f * (float)t) + off;
        float pp   = (grid + 1.0f) * 0.5f * (float)(L_ - 1);
        float fp   = floorf(pp);
        int i0 = (int)fp, i1 = i0 + 1;
        float w = pp - fp;
        float c0 = (i0 >= 0 && i0 < L_) ? (1.0f - w) * mod : 0.0f;
        float c1 = (i1 >= 0 && i1 < L_) ? w * mod : 0.0f;
        int i0c  = min(max(i0, 0), L_ - 1);
        int i1c  = min(max(i1, 0), L_ - 1);
        int i0f2 = min(max(i0, 0), L_ - 2);
        float d0 = (i0c == i0f2     ? c0 : 0.0f) + (i1c == i0f2     ? c1 : 0.0f);
        float d1 = (i0c == i0f2 + 1 ? c0 : 0.0f) + (i1c == i0f2 + 1 ? c1 : 0.0f);
        coef[((size_t)b * 3 + t) * L_ + l] =
            make_float4(d0, d1, __int_as_float(i0f2), 0.0f);
    }
}

// ---------------------------------------------------------------------------
// K2: sample + 2-pass split-precision MFMA GEMM.
// Block 512 thr (8 waves) -> 256o x 64l; wave wv owns o-rows wv*32..+32,
// all 64 cols (n=2 x 32-col frags). K=768 k-major, chunk 128, dbuf LDS.
// acc = Whi*Shi + Wlo*Shi  (W exact to 2^-18, S rounded RNE to bf16)
// ---------------------------------------------------------------------------
__global__ __launch_bounds__(512, 4) void k_conv(
        const float* __restrict__ x,
        const unsigned short* __restrict__ Whi,
        const unsigned short* __restrict__ Wlo,
        const float* __restrict__ bias,
        const float4* __restrict__ coef,
        float* __restrict__ out) {
    __shared__ i32x4 sS[2][16][64];                  // 32 KB total

    const int tid  = threadIdx.x;
    const int lane = tid & 63;
    const int wv   = tid >> 6;                       // 0..7
    const int blk  = blockIdx.x;
    const int b    = blk & 7;                        // XCD affinity
    const int l0   = (blk >> 3) * 64;
    const int q    = lane >> 5;
    const int l31  = lane & 31;

    const float* xb = x + (size_t)b * (C_ * L_);

    // window coefficients for staging column l0+lane, all 3 taps
    int iba[3]; float d0a[3], d1a[3];
    #pragma unroll
    for (int t = 0; t < 3; ++t) {
        float4 cf = coef[((size_t)b * 3 + t) * L_ + l0 + lane];
        d0a[t] = cf.x; d1a[t] = cf.y; iba[t] = __float_as_int(cf.z);
    }

    // A fragment base: row o = wv*32 + l31
    const unsigned short* WhP = Whi + (size_t)(wv * 32 + l31) * 768;
    const unsigned short* WlP = Wlo + (size_t)(wv * 32 + l31) * 768;

    f32x16 acc0, acc1;
    #pragma unroll
    for (int i = 0; i < 16; ++i) { acc0[i] = 0.f; acc1[i] = 0.f; }

    float g0[16], g1[16];

    // ---- prologue: gather + pack chunk 0 (rows wv*16..+16, tap 0) ----
    {
        const float* xc = xb + (size_t)(wv * 16) * L_ + iba[0];
        #pragma unroll
        for (int j = 0; j < 16; ++j) {
            g0[j] = xc[(size_t)j * L_];
            g1[j] = xc[(size_t)j * L_ + 1];
        }
        float d0 = d0a[0], d1 = d1a[0];
        #pragma unroll
        for (int sp = 0; sp < 2; ++sp) {
            union { unsigned short us[8]; i32x4 v; } ph;
            #pragma unroll
            for (int e = 0; e < 8; ++e)
                ph.us[e] = bf16_rne(fmaf(g1[sp * 8 + e], d1, g0[sp * 8 + e] * d0));
            sS[0][wv * 2 + sp][lane] = ph.v;
        }
    }
    __syncthreads();

    #pragma unroll 2
    for (int ch = 0; ch < 6; ++ch) {
        const int buf = ch & 1;
        // ---- prefetch gathers for chunk ch+1 (latency hidden by MFMA) ----
        if (ch < 5) {
            int kk0n = (ch + 1) * 128 + wv * 16;
            int tap  = kk0n >> 8;
            int ib   = tap == 2 ? iba[2] : tap == 1 ? iba[1] : iba[0];
            const float* xc = xb + (size_t)(kk0n & 255) * L_ + ib;
            #pragma unroll
            for (int j = 0; j < 16; ++j) {
                g0[j] = xc[(size_t)j * L_];
                g1[j] = xc[(size_t)j * L_ + 1];
            }
        }
        // ---- MFMA phase: 8 K-steps of 16, A ping-pong prefetch ----
        {
            const int kb = ch * 128 + q * 8;
            bf16x8 aH0 = *(const bf16x8*)(WhP + kb);
            bf16x8 aL0 = *(const bf16x8*)(WlP + kb);
            #pragma unroll
            for (int ks2 = 0; ks2 < 4; ++ks2) {
                bf16x8 aH1 = *(const bf16x8*)(WhP + kb + (ks2 * 2 + 1) * 16);
                bf16x8 aL1 = *(const bf16x8*)(WlP + kb + (ks2 * 2 + 1) * 16);
                {
                    const i32x4* bp = &sS[buf][ks2 * 4 + q][l31];
                    bf16x8 bh0 = *(const bf16x8*)bp;
                    bf16x8 bh1 = *(const bf16x8*)(bp + 32);
                    __builtin_amdgcn_s_setprio(1);
                    acc0 = __builtin_amdgcn_mfma_f32_32x32x16_bf16(aH0, bh0, acc0, 0, 0, 0);
                    acc0 = __builtin_amdgcn_mfma_f32_32x32x16_bf16(aL0, bh0, acc0, 0, 0, 0);
                    acc1 = __builtin_amdgcn_mfma_f32_32x32x16_bf16(aH0, bh1, acc1, 0, 0, 0);
                    acc1 = __builtin_amdgcn_mfma_f32_32x32x16_bf16(aL0, bh1, acc1, 0, 0, 0);
                    __builtin_amdgcn_s_setprio(0);
                }
                if (ks2 < 3) {
                    aH0 = *(const bf16x8*)(WhP + kb + (ks2 * 2 + 2) * 16);
                    aL0 = *(const bf16x8*)(WlP + kb + (ks2 * 2 + 2) * 16);
                }
                {
                    const i32x4* bp = &sS[buf][ks2 * 4 + 2 + q][l31];
                    bf16x8 bh0 = *(const bf16x8*)bp;
                    bf16x8 bh1 = *(const bf16x8*)(bp + 32);
                    __builtin_amdgcn_s_setprio(1);
                    acc0 = __builtin_amdgcn_mfma_f32_32x32x16_bf16(aH1, bh0, acc0, 0, 0, 0);
                    acc0 = __builtin_amdgcn_mfma_f32_32x32x16_bf16(aL1, bh0, acc0, 0, 0, 0);
                    acc1 = __builtin_amdgcn_mfma_f32_32x32x16_bf16(aH1, bh1, acc1, 0, 0, 0);
                    acc1 = __builtin_amdgcn_mfma_f32_32x32x16_bf16(aL1, bh1, acc1, 0, 0, 0);
                    __builtin_amdgcn_s_setprio(0);
                }
            }
        }
        // ---- pack + write chunk ch+1 into other buffer ----
        if (ch < 5) {
            int kk0n = (ch + 1) * 128 + wv * 16;
            int tap  = kk0n >> 8;
            float d0 = tap == 2 ? d0a[2] : tap == 1 ? d0a[1] : d0a[0];
            float d1 = tap == 2 ? d1a[2] : tap == 1 ? d1a[1] : d1a[0];
            const int nbuf = buf ^ 1;
            #pragma unroll
            for (int sp = 0; sp < 2; ++sp) {
                union { unsigned short us[8]; i32x4 v; } ph;
                #pragma unroll
                for (int e = 0; e < 8; ++e)
                    ph.us[e] = bf16_rne(fmaf(g1[sp * 8 + e], d1, g0[sp * 8 + e] * d0));
                sS[nbuf][wv * 2 + sp][lane] = ph.v;
            }
        }
        __syncthreads();
    }

    // ---- epilogue: bias + store. D: col=lane&31, row=(reg&3)+8*(reg>>2)+4*q
    #pragma unroll
    for (int reg = 0; reg < 16; ++reg) {
        int rr = (reg & 3) + 8 * (reg >> 2) + 4 * q;
        int o  = wv * 32 + rr;
        float bv = bias[o];
        float* op = out + ((size_t)b * 256 + o) * L_ + l0 + l31;
        op[0]  = acc0[reg] + bv;
        op[32] = acc1[reg] + bv;
    }
}

// ---------------------------------------------------------------------------
extern "C" void kernel_launch(void* const* d_in, const int* in_sizes, int n_in,
                              void* d_out, int out_size, void* d_ws, size_t ws_size,
                              hipStream_t stream) {
    const float* x      = (const float*)d_in[0];
    const float* weight = (const float*)d_in[1];
    const float* bias   = (const float*)d_in[2];
    const float* w1     = (const float*)d_in[3];
    const float* b1     = (const float*)d_in[4];
    const float* w2     = (const float*)d_in[5];
    const float* b2     = (const float*)d_in[6];
    float* out = (float*)d_out;

    char* ws = (char*)d_ws;
    float4* coef = (float4*)ws;                                   // 1.5 MB
    unsigned short* Whi = (unsigned short*)(ws + (size_t)B_ * 3 * L_ * sizeof(float4));
    unsigned short* Wlo = Whi + OCH_ * C_ * 3;                    // +384 KB each

    k_split<<<(OCH_ * C_ * 3 + 255) / 256, 256, 0, stream>>>(weight, Whi, Wlo);
    k_offsets<<<B_ * (L_ / 64), 256, 0, stream>>>(x, w1, b1, w2, b2, coef);
    k_conv<<<B_ * (L_ / 64), 512, 0, stream>>>(x, Whi, Wlo, bias, coef, out);
}